// Round 5
// baseline (259.366 us; speedup 1.0000x reference)
//
#include <hip/hip_runtime.h>
#include <cmath>

#define NTOK 32768
#define HDIM 512
#define GVDIM 640
#define VDIM 320
#define DG 128
#define OUT0_SIZE (NTOK * 256)
#define MARGIN 0.02f

typedef __attribute__((ext_vector_type(8))) short s16x8;
typedef __attribute__((ext_vector_type(8))) unsigned short u16x8;
typedef __attribute__((ext_vector_type(8))) _Float16 h16x8;
typedef __attribute__((ext_vector_type(4))) float f32x4;

__device__ __forceinline__ unsigned short f2bf(float f) {
    unsigned u = __float_as_uint(f);
    return (unsigned short)((u + 0x7FFFu + ((u >> 16) & 1u)) >> 16);  // RTN
}

// ---------------- hs fp32 -> bf16 (8 elems/thread) ----------------
__global__ __launch_bounds__(256) void k_cvt_hs(const float* __restrict__ hs,
                                                unsigned short* __restrict__ dst) {
    int i = blockIdx.x * 256 + threadIdx.x;
    const float4* s = (const float4*)hs + (size_t)i * 2;
    float4 a = s[0], b = s[1];
    u16x8 o;
    o[0] = f2bf(a.x); o[1] = f2bf(a.y); o[2] = f2bf(a.z); o[3] = f2bf(a.w);
    o[4] = f2bf(b.x); o[5] = f2bf(b.y); o[6] = f2bf(b.z); o[7] = f2bf(b.w);
    *((u16x8*)dst + i) = o;
}

// ---- W [512][640] fp32 -> Wt [640][512] bf16 (+ zero hist & list ctr) ----
__global__ __launch_bounds__(256) void k_cvt_wt(const float* __restrict__ W,
                                                unsigned short* __restrict__ Wt,
                                                int* __restrict__ hist,
                                                int* __restrict__ ctr) {
    int n = blockIdx.x;
    if (threadIdx.x == 0) hist[n] = 0;
    if (n == 0 && threadIdx.x == 1) ctr[0] = 0;
#pragma unroll
    for (int k2 = 0; k2 < 2; ++k2) {
        int k = k2 * 256 + threadIdx.x;
        Wt[(size_t)n * 512 + k] = f2bf(W[(size_t)k * 640 + n]);
    }
}

// ---------------- MFMA GEMM: logits = hs_bf16 . Wt^T + bias -> fp16 ------
__global__ __launch_bounds__(256) void k_gemm(
    const unsigned short* __restrict__ A,   // [NTOK][512] bf16
    const unsigned short* __restrict__ Bt,  // [640][512] bf16
    const float* __restrict__ bias,
    _Float16* __restrict__ logits)          // [NTOK][640]
{
    __shared__ short As[128 * 64];
    __shared__ short Bs[128 * 64];

    const int tid  = threadIdx.x;
    const int lane = tid & 63;
    const int wid  = __builtin_amdgcn_readfirstlane(tid >> 6);
    const int mb   = blockIdx.x & 255;
    const int nb   = blockIdx.x >> 8;
    const int tok0 = mb * 128;
    const int col0 = nb * 128;

    const int r8 = lane >> 3;
    const int c8 = lane & 7;
    const int cl = c8 ^ r8;

    const unsigned short* gA = A  + (size_t)(tok0 + wid * 32 + r8) * 512 + cl * 8;
    const unsigned short* gB = Bt + (size_t)(col0 + wid * 32 + r8) * 512 + cl * 8;

    const int quad = lane >> 4;
    const int m16  = lane & 15;
    const int wm   = (wid >> 1) * 64;
    const int wn   = (wid & 1) * 64;

    f32x4 acc[4][4];
#pragma unroll
    for (int mt = 0; mt < 4; ++mt)
#pragma unroll
        for (int nt = 0; nt < 4; ++nt) acc[mt][nt] = (f32x4){0.f, 0.f, 0.f, 0.f};

    for (int kb = 0; kb < 8; ++kb) {
#pragma unroll
        for (int i = 0; i < 4; ++i) {
            __builtin_amdgcn_global_load_lds(
                (__attribute__((address_space(1))) void*)(gA + (size_t)i * 8 * 512 + kb * 64),
                (__attribute__((address_space(3))) void*)(As + (wid * 32 + i * 8) * 64),
                16, 0, 0);
            __builtin_amdgcn_global_load_lds(
                (__attribute__((address_space(1))) void*)(gB + (size_t)i * 8 * 512 + kb * 64),
                (__attribute__((address_space(3))) void*)(Bs + (wid * 32 + i * 8) * 64),
                16, 0, 0);
        }
        __syncthreads();
#pragma unroll
        for (int ks = 0; ks < 2; ++ks) {
            s16x8 af[4], bf[4];
            const int kch = ks * 4 + quad;
#pragma unroll
            for (int t = 0; t < 4; ++t) {
                int arow = wm + t * 16 + m16;
                af[t] = *(const s16x8*)(As + arow * 64 + (kch ^ (arow & 7)) * 8);
                int brow = wn + t * 16 + m16;
                bf[t] = *(const s16x8*)(Bs + brow * 64 + (kch ^ (brow & 7)) * 8);
            }
#pragma unroll
            for (int mt = 0; mt < 4; ++mt)
#pragma unroll
                for (int nt = 0; nt < 4; ++nt)
                    acc[mt][nt] = __builtin_amdgcn_mfma_f32_16x16x32_bf16(
                        af[mt], bf[nt], acc[mt][nt], 0, 0, 0);
        }
        __syncthreads();
    }

    float bv[4];
#pragma unroll
    for (int nt = 0; nt < 4; ++nt) bv[nt] = bias[col0 + wn + nt * 16 + m16];

#pragma unroll
    for (int mt = 0; mt < 4; ++mt) {
#pragma unroll
        for (int r = 0; r < 4; ++r) {
            int token = tok0 + wm + mt * 16 + quad * 4 + r;
            _Float16* dst = logits + (size_t)token * 640 + col0 + wn + m16;
#pragma unroll
            for (int nt = 0; nt < 4; ++nt)
                dst[nt * 16] = (_Float16)(acc[mt][nt][r] + bv[nt]);
        }
    }
}

// ---- phase A: scan (8 lanes per token-group) + fused gather -------------
// wave covers 8 consecutive token-groups; lane = (row<<3)|sub.
// Each lane: 5 x 16B coalesced loads; 3 shuffle steps per reduction.
__global__ __launch_bounds__(256) void k_scan_gather(
    const _Float16* __restrict__ logits, const float* __restrict__ cb,
    float* __restrict__ out, int* __restrict__ idx_out,
    int* __restrict__ hist, int* __restrict__ ctr, int2* __restrict__ list)
{
    const int lane = threadIdx.x & 63;
    const int sub  = lane & 7;
    const int wv   = (blockIdx.x * 256 + threadIdx.x) >> 6;  // 8192 waves
    const int tg   = wv * 8 + (lane >> 3);
    const int tok  = tg >> 1;
    const int grp  = tg & 1;

    const h16x8* row = (const h16x8*)(logits + (size_t)tg * 320);
    h16x8 v[5];
#pragma unroll
    for (int i = 0; i < 5; ++i) v[i] = row[sub + i * 8];

    // per-thread max over 40 values
    h16x8 m01 = __builtin_elementwise_max(v[0], v[1]);
    h16x8 m23 = __builtin_elementwise_max(v[2], v[3]);
    h16x8 mm  = __builtin_elementwise_max(__builtin_elementwise_max(m01, m23), v[4]);
    float M = (float)mm[0];
#pragma unroll
    for (int h = 1; h < 8; ++h) M = fmaxf(M, (float)mm[h]);
    // combine across the 8 lanes of this row
#pragma unroll
    for (int off = 1; off <= 4; off <<= 1) M = fmaxf(M, __shfl_xor(M, off));

    const float thr = M - MARGIN;
    int first = 0x7FFFFFFF, cnt = 0;
#pragma unroll
    for (int i = 0; i < 5; ++i) {
#pragma unroll
        for (int h = 0; h < 8; ++h) {
            float f = (float)v[i][h];
            if (f >= thr) {
                int col = sub * 8 + i * 64 + h;
                if (col < first) first = col;
                ++cnt;
            }
        }
    }
#pragma unroll
    for (int off = 1; off <= 4; off <<= 1) {
        first = min(first, __shfl_xor(first, off));
        cnt  += __shfl_xor(cnt, off);
    }

    if (cnt == 1) {
        if (sub == 0) {
            idx_out[tg] = first;
            atomicAdd(&hist[grp * VDIM + first], 1);
        }
        // fused gather: 8 lanes write this tg's 512B out row
        const float4* src = (const float4*)(cb + (size_t)(grp * VDIM + first) * DG);
        float4* dst = (float4*)(out + (size_t)tok * 256 + grp * 128);
#pragma unroll
        for (int i = 0; i < 4; ++i) dst[sub + i * 8] = src[sub + i * 8];
    } else if (sub == 0) {
        int p = atomicAdd(ctr, 1);
        list[p] = make_int2(tg, __float_as_int(thr));
    }
}

// ---- phase B: exact fp32 rescore of flagged token-groups + gather -------
__global__ __launch_bounds__(256) void k_rescore(
    const _Float16* __restrict__ logits, const float* __restrict__ hs,
    const float* __restrict__ W, const float* __restrict__ bias,
    const float* __restrict__ cb, float* __restrict__ out,
    const int2* __restrict__ list, const int* __restrict__ ctr,
    int* __restrict__ idx_out, int* __restrict__ hist)
{
    const int lane  = threadIdx.x & 63;
    const int wslot = blockIdx.x * 4 + (threadIdx.x >> 6);
    const int n = ctr[0];

    for (int it = wslot; it < n; it += 4096) {
        const int2 rec = list[it];
        const int tok = rec.x >> 1;
        const int grp = rec.x & 1;
        const float thr = __int_as_float(rec.y);

        const _Float16* lp = logits + (size_t)tok * 640 + grp * 320;
        float hsr[8];
#pragma unroll
        for (int i = 0; i < 8; ++i) hsr[i] = hs[(size_t)tok * 512 + i * 64 + lane];

        float bestv = -INFINITY;
        int   besti = 0;
#pragma unroll
        for (int j = 0; j < 5; ++j) {
            float vv = (float)lp[j * 64 + lane];
            unsigned long long mk = __ballot(vv >= thr);
            while (mk) {
                int b = __ffsll(mk) - 1; mk &= mk - 1;
                int col  = j * 64 + b;
                int gcol = grp * VDIM + col;
                float p = 0.f;
#pragma unroll
                for (int i = 0; i < 8; ++i)
                    p = fmaf(hsr[i], W[(size_t)(i * 64 + lane) * 640 + gcol], p);
#pragma unroll
                for (int off = 32; off >= 1; off >>= 1) p += __shfl_xor(p, off);
                float val = p + bias[gcol];
                if (val > bestv) { bestv = val; besti = col; }  // first-max
            }
        }
        if (lane == 0) {
            idx_out[rec.x] = besti;
            atomicAdd(&hist[grp * VDIM + besti], 1);
        }
        // fused gather: 64 lanes x float2 = 512B out row
        besti = __shfl(besti, 0);
        float2 cv = ((const float2*)(cb + (size_t)(grp * VDIM + besti) * DG))[lane];
        ((float2*)(out + (size_t)tok * 256 + grp * 128))[lane] = cv;
    }
}

// ---------------- perplexity ----------------
__global__ void k_perplex(const int* __restrict__ hist, float* __restrict__ out)
{
    __shared__ float sh[GVDIM];
    int t = threadIdx.x;
    float p = (float)hist[t] * (1.0f / (float)NTOK);
    sh[t] = p * logf(p + 1e-7f);
    __syncthreads();
    if (t == 0) {
        float s0 = 0.f, s1 = 0.f;
        for (int i = 0; i < VDIM; ++i)  s0 += sh[i];
        for (int i = VDIM; i < GVDIM; ++i) s1 += sh[i];
        out[0] = expf(-s0) + expf(-s1);
    }
}

extern "C" void kernel_launch(void* const* d_in, const int* in_sizes, int n_in,
                              void* d_out, int out_size, void* d_ws, size_t ws_size,
                              hipStream_t stream)
{
    const float* hs   = (const float*)d_in[0];
    const float* W    = (const float*)d_in[1];
    const float* bias = (const float*)d_in[2];
    const float* cb   = (const float*)d_in[3];

    unsigned short* hsb = (unsigned short*)d_ws;          // 16,777,216 bf16
    unsigned short* wt  = hsb + 16777216;                 // 327,680 bf16
    _Float16* logits    = (_Float16*)(wt + 327680);       // 20,971,520 fp16
    int* idx            = (int*)(logits + 20971520);      // 65,536 int
    int* hist           = idx + 65536;                    // 640 int
    int* ctr            = hist + GVDIM;                   // 1 int (+1 pad)
    int2* list          = (int2*)(ctr + 2);               // up to 65,536 int2

    float* out  = (float*)d_out;
    float* perp = out + OUT0_SIZE;

    hipLaunchKernelGGL(k_cvt_hs,      dim3(8192),  dim3(256), 0, stream, hs, hsb);
    hipLaunchKernelGGL(k_cvt_wt,      dim3(GVDIM), dim3(256), 0, stream, W, wt, hist, ctr);
    hipLaunchKernelGGL(k_gemm,        dim3(1280),  dim3(256), 0, stream, hsb, wt, bias, logits);
    hipLaunchKernelGGL(k_scan_gather, dim3(2048),  dim3(256), 0, stream,
                       logits, cb, out, idx, hist, ctr, list);
    hipLaunchKernelGGL(k_rescore,     dim3(1024),  dim3(256), 0, stream,
                       logits, hs, W, bias, cb, out, list, ctr, idx, hist);
    hipLaunchKernelGGL(k_perplex,     dim3(1),     dim3(GVDIM), 0, stream, hist, perp);
}

// Round 6
// 217.801 us; speedup vs baseline: 1.1908x; 1.1908x over previous
//
#include <hip/hip_runtime.h>
#include <cmath>

#define NTOK 32768
#define HDIM 512
#define GVDIM 640
#define VDIM 320
#define DG 128
#define OUT0_SIZE (NTOK * 256)
#define MARGIN 0.02f

typedef __attribute__((ext_vector_type(8))) short s16x8;
typedef __attribute__((ext_vector_type(8))) unsigned short u16x8;
typedef __attribute__((ext_vector_type(4))) float f32x4;

__device__ __forceinline__ unsigned short f2bf(float f) {
    unsigned u = __float_as_uint(f);
    return (unsigned short)((u + 0x7FFFu + ((u >> 16) & 1u)) >> 16);  // RTN
}

// ---------------- hs fp32 -> bf16 (8 elems/thread) ----------------
__global__ __launch_bounds__(256) void k_cvt_hs(const float* __restrict__ hs,
                                                unsigned short* __restrict__ dst) {
    int i = blockIdx.x * 256 + threadIdx.x;
    const float4* s = (const float4*)hs + (size_t)i * 2;
    float4 a = s[0], b = s[1];
    u16x8 o;
    o[0] = f2bf(a.x); o[1] = f2bf(a.y); o[2] = f2bf(a.z); o[3] = f2bf(a.w);
    o[4] = f2bf(b.x); o[5] = f2bf(b.y); o[6] = f2bf(b.z); o[7] = f2bf(b.w);
    *((u16x8*)dst + i) = o;
}

// ---- W [512][640] fp32 -> Wt [640][512] bf16 (+ zero hist & list ctr) ----
__global__ __launch_bounds__(256) void k_cvt_wt(const float* __restrict__ W,
                                                unsigned short* __restrict__ Wt,
                                                int* __restrict__ hist,
                                                int* __restrict__ ctr) {
    int n = blockIdx.x;
    if (threadIdx.x == 0) hist[n] = 0;
    if (n == 0 && threadIdx.x == 1) ctr[0] = 0;
#pragma unroll
    for (int k2 = 0; k2 < 2; ++k2) {
        int k = k2 * 256 + threadIdx.x;
        Wt[(size_t)n * 512 + k] = f2bf(W[(size_t)k * 640 + n]);
    }
}

// ---- MFMA GEMM with fused chunk-reduction epilogue (NO logits output) ----
// Per (token, 64-col chunk): meta = {bf16-path max, mask64 of cols within
// MARGIN of that max}. 16 B per entry, [token][10 chunks].
__global__ __launch_bounds__(256) void k_gemm(
    const unsigned short* __restrict__ A,   // [NTOK][512] bf16
    const unsigned short* __restrict__ Bt,  // [640][512] bf16
    const float* __restrict__ bias,
    uint4* __restrict__ meta)               // [NTOK][10]
{
    __shared__ short As[128 * 64];
    __shared__ short Bs[128 * 64];

    const int tid  = threadIdx.x;
    const int lane = tid & 63;
    const int wid  = __builtin_amdgcn_readfirstlane(tid >> 6);
    const int mb   = blockIdx.x & 255;
    const int nb   = blockIdx.x >> 8;
    const int tok0 = mb * 128;
    const int col0 = nb * 128;

    const int r8 = lane >> 3;
    const int c8 = lane & 7;
    const int cl = c8 ^ r8;

    const unsigned short* gA = A  + (size_t)(tok0 + wid * 32 + r8) * 512 + cl * 8;
    const unsigned short* gB = Bt + (size_t)(col0 + wid * 32 + r8) * 512 + cl * 8;

    const int quad = lane >> 4;
    const int m16  = lane & 15;
    const int wm   = (wid >> 1) * 64;
    const int wn   = (wid & 1) * 64;

    f32x4 acc[4][4];
#pragma unroll
    for (int mt = 0; mt < 4; ++mt)
#pragma unroll
        for (int nt = 0; nt < 4; ++nt) acc[mt][nt] = (f32x4){0.f, 0.f, 0.f, 0.f};

    for (int kb = 0; kb < 8; ++kb) {
#pragma unroll
        for (int i = 0; i < 4; ++i) {
            __builtin_amdgcn_global_load_lds(
                (__attribute__((address_space(1))) void*)(gA + (size_t)i * 8 * 512 + kb * 64),
                (__attribute__((address_space(3))) void*)(As + (wid * 32 + i * 8) * 64),
                16, 0, 0);
            __builtin_amdgcn_global_load_lds(
                (__attribute__((address_space(1))) void*)(gB + (size_t)i * 8 * 512 + kb * 64),
                (__attribute__((address_space(3))) void*)(Bs + (wid * 32 + i * 8) * 64),
                16, 0, 0);
        }
        __syncthreads();
#pragma unroll
        for (int ks = 0; ks < 2; ++ks) {
            s16x8 af[4], bf[4];
            const int kch = ks * 4 + quad;
#pragma unroll
            for (int t = 0; t < 4; ++t) {
                int arow = wm + t * 16 + m16;
                af[t] = *(const s16x8*)(As + arow * 64 + (kch ^ (arow & 7)) * 8);
                int brow = wn + t * 16 + m16;
                bf[t] = *(const s16x8*)(Bs + brow * 64 + (kch ^ (brow & 7)) * 8);
            }
#pragma unroll
            for (int mt = 0; mt < 4; ++mt)
#pragma unroll
                for (int nt = 0; nt < 4; ++nt)
                    acc[mt][nt] = __builtin_amdgcn_mfma_f32_16x16x32_bf16(
                        af[mt], bf[nt], acc[mt][nt], 0, 0, 0);
        }
        __syncthreads();
    }

    float bv[4];
#pragma unroll
    for (int nt = 0; nt < 4; ++nt) bv[nt] = bias[col0 + wn + nt * 16 + m16];

    // ---- fused reduction epilogue: this wave owns chunk ch (64 cols) ----
    const int ch = (col0 + wn) >> 6;          // global chunk 0..9
#pragma unroll
    for (int mt = 0; mt < 4; ++mt) {
#pragma unroll
        for (int r = 0; r < 4; ++r) {
            float v0 = acc[mt][0][r] + bv[0];
            float v1 = acc[mt][1][r] + bv[1];
            float v2 = acc[mt][2][r] + bv[2];
            float v3 = acc[mt][3][r] + bv[3];
            float cmax = fmaxf(fmaxf(v0, v1), fmaxf(v2, v3));
#pragma unroll
            for (int off = 1; off <= 8; off <<= 1)
                cmax = fmaxf(cmax, __shfl_xor(cmax, off));   // over m16 lanes
            const float t = cmax - MARGIN;
            unsigned long long b0 = __ballot(v0 >= t);
            unsigned long long b1 = __ballot(v1 >= t);
            unsigned long long b2 = __ballot(v2 >= t);
            unsigned long long b3 = __ballot(v3 >= t);
            if (m16 == 0) {
                unsigned q16 = quad * 16;
                unsigned long long mask =
                      (((b0 >> q16) & 0xFFFFull))
                    | (((b1 >> q16) & 0xFFFFull) << 16)
                    | (((b2 >> q16) & 0xFFFFull) << 32)
                    | (((b3 >> q16) & 0xFFFFull) << 48);
                int token = tok0 + wm + mt * 16 + quad * 4 + r;
                uint4 e;
                e.x = __float_as_uint(cmax);
                e.y = (unsigned)(mask & 0xFFFFFFFFull);
                e.z = (unsigned)(mask >> 32);
                e.w = 0;
                meta[(size_t)token * 10 + ch] = e;
            }
        }
    }
}

// ---- decide: fast-path argmax from 5 chunk metas, else flag for rescore ----
__global__ __launch_bounds__(256) void k_decide(
    const uint4* __restrict__ meta, int* __restrict__ idx_out,
    int* __restrict__ hist, int* __restrict__ ctr, int* __restrict__ list)
{
    const int tg  = blockIdx.x * 256 + threadIdx.x;   // 65536
    const int tok = tg >> 1;
    const int grp = tg & 1;

    const uint4* mp = meta + (size_t)tok * 10 + grp * 5;
    float pm[5]; unsigned long long mk[5];
#pragma unroll
    for (int j = 0; j < 5; ++j) {
        uint4 e = mp[j];
        pm[j] = __uint_as_float(e.x);
        mk[j] = ((unsigned long long)e.z << 32) | e.y;
    }
    float M = fmaxf(fmaxf(fmaxf(pm[0], pm[1]), fmaxf(pm[2], pm[3])), pm[4]);
    const float thr = M - MARGIN;

    int nq = 0, qc = 0;
#pragma unroll
    for (int j = 0; j < 5; ++j)
        if (pm[j] >= thr) { ++nq; qc = j; }

    if (nq == 1 && __popcll(mk[qc]) == 1) {
        int col = qc * 64 + (__ffsll((long long)mk[qc]) - 1);
        idx_out[tg] = col;
        atomicAdd(&hist[grp * VDIM + col], 1);
    } else {
        int p = atomicAdd(ctr, 1);
        list[p] = tg;
    }
}

// ---- rescore: exact fp32 dot for every candidate col of flagged tgs ----
__global__ __launch_bounds__(256) void k_rescore(
    const uint4* __restrict__ meta, const float* __restrict__ hs,
    const float* __restrict__ W, const float* __restrict__ bias,
    const int* __restrict__ list, const int* __restrict__ ctr,
    int* __restrict__ idx_out, int* __restrict__ hist)
{
    const int lane  = threadIdx.x & 63;
    const int wslot = blockIdx.x * 4 + (threadIdx.x >> 6);
    const int n = ctr[0];

    for (int it = wslot; it < n; it += 8192) {
        const int tg  = list[it];
        const int tok = tg >> 1;
        const int grp = tg & 1;

        const uint4* mp = meta + (size_t)tok * 10 + grp * 5;
        float pm[5]; unsigned long long mk[5];
#pragma unroll
        for (int j = 0; j < 5; ++j) {
            uint4 e = mp[j];
            pm[j] = __uint_as_float(e.x);
            mk[j] = ((unsigned long long)e.z << 32) | e.y;
        }
        float M = fmaxf(fmaxf(fmaxf(pm[0], pm[1]), fmaxf(pm[2], pm[3])), pm[4]);
        const float thr = M - MARGIN;

        float hsr[8];
#pragma unroll
        for (int i = 0; i < 8; ++i) hsr[i] = hs[(size_t)tok * 512 + i * 64 + lane];

        float bestv = -INFINITY;
        int   besti = 0;
#pragma unroll
        for (int j = 0; j < 5; ++j) {
            if (pm[j] < thr) continue;
            unsigned long long m = mk[j];
            while (m) {
                int b = __ffsll((long long)m) - 1; m &= m - 1;
                int col  = j * 64 + b;
                int gcol = grp * VDIM + col;
                float p = 0.f;
#pragma unroll
                for (int i = 0; i < 8; ++i)
                    p = fmaf(hsr[i], W[(size_t)(i * 64 + lane) * 640 + gcol], p);
#pragma unroll
                for (int off = 32; off >= 1; off >>= 1) p += __shfl_xor(p, off);
                float val = p + bias[gcol];
                if (val > bestv) { bestv = val; besti = col; }  // asc col => first-max
            }
        }
        if (lane == 0) {
            idx_out[tg] = besti;
            atomicAdd(&hist[grp * VDIM + besti], 1);
        }
    }
}

// ---------------- gather codevectors (all tokens) ----------------
__global__ __launch_bounds__(256) void k_gather(
    const float* __restrict__ cb, const int* __restrict__ idx,
    float* __restrict__ out)
{
    int tid  = threadIdx.x;
    int t    = blockIdx.x * 4 + (tid >> 6);
    int lane = tid & 63;
    int g    = lane >> 5;
    int q    = lane & 31;
    int i    = idx[t * 2 + g];
    const float4* src = (const float4*)(cb + (size_t)(g * VDIM + i) * DG);
    float4 v = src[q];
    ((float4*)(out + (size_t)t * 256))[g * 32 + q] = v;
}

// ---------------- perplexity ----------------
__global__ void k_perplex(const int* __restrict__ hist, float* __restrict__ out)
{
    __shared__ float sh[GVDIM];
    int t = threadIdx.x;
    float p = (float)hist[t] * (1.0f / (float)NTOK);
    sh[t] = p * logf(p + 1e-7f);
    __syncthreads();
    if (t == 0) {
        float s0 = 0.f, s1 = 0.f;
        for (int i = 0; i < VDIM; ++i)  s0 += sh[i];
        for (int i = VDIM; i < GVDIM; ++i) s1 += sh[i];
        out[0] = expf(-s0) + expf(-s1);
    }
}

extern "C" void kernel_launch(void* const* d_in, const int* in_sizes, int n_in,
                              void* d_out, int out_size, void* d_ws, size_t ws_size,
                              hipStream_t stream)
{
    const float* hs   = (const float*)d_in[0];
    const float* W    = (const float*)d_in[1];
    const float* bias = (const float*)d_in[2];
    const float* cb   = (const float*)d_in[3];

    unsigned short* hsb = (unsigned short*)d_ws;          // 32 MB
    unsigned short* wt  = hsb + 16777216;                 // 640 KB
    uint4* meta         = (uint4*)(wt + 327680);          // 32768*10*16 B
    int* idx            = (int*)(meta + 327680);          // 65,536 int
    int* hist           = idx + 65536;                    // 640 int
    int* ctr            = hist + GVDIM;                   // 1 int (+1 pad)
    int* list           = ctr + 2;                        // up to 65,536 int

    float* out  = (float*)d_out;
    float* perp = out + OUT0_SIZE;

    hipLaunchKernelGGL(k_cvt_hs,  dim3(8192),  dim3(256), 0, stream, hs, hsb);
    hipLaunchKernelGGL(k_cvt_wt,  dim3(GVDIM), dim3(256), 0, stream, W, wt, hist, ctr);
    hipLaunchKernelGGL(k_gemm,    dim3(1280),  dim3(256), 0, stream, hsb, wt, bias, meta);
    hipLaunchKernelGGL(k_decide,  dim3(256),   dim3(256), 0, stream,
                       meta, idx, hist, ctr, list);
    hipLaunchKernelGGL(k_rescore, dim3(2048),  dim3(256), 0, stream,
                       meta, hs, W, bias, list, ctr, idx, hist);
    hipLaunchKernelGGL(k_gather,  dim3(8192),  dim3(256), 0, stream, cb, idx, out);
    hipLaunchKernelGGL(k_perplex, dim3(1),     dim3(GVDIM), 0, stream, hist, perp);
}

// Round 7
// 186.081 us; speedup vs baseline: 1.3938x; 1.1705x over previous
//
#include <hip/hip_runtime.h>
#include <cmath>

#define NTOK 32768
#define HDIM 512
#define GVDIM 640
#define VDIM 320
#define DG 128
#define OUT0_SIZE (NTOK * 256)
#define MARGIN 0.02f

typedef __attribute__((ext_vector_type(8))) short s16x8;
typedef __attribute__((ext_vector_type(8))) unsigned short u16x8;
typedef __attribute__((ext_vector_type(4))) float f32x4;

__device__ __forceinline__ unsigned short f2bf(float f) {
    unsigned u = __float_as_uint(f);
    return (unsigned short)((u + 0x7FFFu + ((u >> 16) & 1u)) >> 16);  // RTN
}

// ---------------- hs fp32 -> bf16 (8 elems/thread) ----------------
__global__ __launch_bounds__(256) void k_cvt_hs(const float* __restrict__ hs,
                                                unsigned short* __restrict__ dst) {
    int i = blockIdx.x * 256 + threadIdx.x;
    const float4* s = (const float4*)hs + (size_t)i * 2;
    float4 a = s[0], b = s[1];
    u16x8 o;
    o[0] = f2bf(a.x); o[1] = f2bf(a.y); o[2] = f2bf(a.z); o[3] = f2bf(a.w);
    o[4] = f2bf(b.x); o[5] = f2bf(b.y); o[6] = f2bf(b.z); o[7] = f2bf(b.w);
    *((u16x8*)dst + i) = o;
}

// -- W [512][640] fp32 -> Wt bf16 [640][512] + Wt32 fp32 [640][512] --------
// (+ zero hist & list ctr)
__global__ __launch_bounds__(256) void k_cvt_wt(const float* __restrict__ W,
                                                unsigned short* __restrict__ Wt,
                                                float* __restrict__ Wt32,
                                                int* __restrict__ hist,
                                                int* __restrict__ ctr) {
    int n = blockIdx.x;
    if (threadIdx.x == 0) hist[n] = 0;
    if (n == 0 && threadIdx.x == 1) ctr[0] = 0;
#pragma unroll
    for (int k2 = 0; k2 < 2; ++k2) {
        int k = k2 * 256 + threadIdx.x;
        float w = W[(size_t)k * 640 + n];
        Wt[(size_t)n * 512 + k]   = f2bf(w);
        Wt32[(size_t)n * 512 + k] = w;
    }
}

// ---- MFMA GEMM with fused chunk-reduction epilogue (NO logits output) ----
__global__ __launch_bounds__(256) void k_gemm(
    const unsigned short* __restrict__ A,   // [NTOK][512] bf16
    const unsigned short* __restrict__ Bt,  // [640][512] bf16
    const float* __restrict__ bias,
    uint4* __restrict__ meta)               // [NTOK][10]
{
    __shared__ short As[128 * 64];
    __shared__ short Bs[128 * 64];

    const int tid  = threadIdx.x;
    const int lane = tid & 63;
    const int wid  = __builtin_amdgcn_readfirstlane(tid >> 6);
    const int mb   = blockIdx.x & 255;
    const int nb   = blockIdx.x >> 8;
    const int tok0 = mb * 128;
    const int col0 = nb * 128;

    const int r8 = lane >> 3;
    const int c8 = lane & 7;
    const int cl = c8 ^ r8;

    const unsigned short* gA = A  + (size_t)(tok0 + wid * 32 + r8) * 512 + cl * 8;
    const unsigned short* gB = Bt + (size_t)(col0 + wid * 32 + r8) * 512 + cl * 8;

    const int quad = lane >> 4;
    const int m16  = lane & 15;
    const int wm   = (wid >> 1) * 64;
    const int wn   = (wid & 1) * 64;

    f32x4 acc[4][4];
#pragma unroll
    for (int mt = 0; mt < 4; ++mt)
#pragma unroll
        for (int nt = 0; nt < 4; ++nt) acc[mt][nt] = (f32x4){0.f, 0.f, 0.f, 0.f};

    for (int kb = 0; kb < 8; ++kb) {
#pragma unroll
        for (int i = 0; i < 4; ++i) {
            __builtin_amdgcn_global_load_lds(
                (__attribute__((address_space(1))) void*)(gA + (size_t)i * 8 * 512 + kb * 64),
                (__attribute__((address_space(3))) void*)(As + (wid * 32 + i * 8) * 64),
                16, 0, 0);
            __builtin_amdgcn_global_load_lds(
                (__attribute__((address_space(1))) void*)(gB + (size_t)i * 8 * 512 + kb * 64),
                (__attribute__((address_space(3))) void*)(Bs + (wid * 32 + i * 8) * 64),
                16, 0, 0);
        }
        __syncthreads();
#pragma unroll
        for (int ks = 0; ks < 2; ++ks) {
            s16x8 af[4], bf[4];
            const int kch = ks * 4 + quad;
#pragma unroll
            for (int t = 0; t < 4; ++t) {
                int arow = wm + t * 16 + m16;
                af[t] = *(const s16x8*)(As + arow * 64 + (kch ^ (arow & 7)) * 8);
                int brow = wn + t * 16 + m16;
                bf[t] = *(const s16x8*)(Bs + brow * 64 + (kch ^ (brow & 7)) * 8);
            }
#pragma unroll
            for (int mt = 0; mt < 4; ++mt)
#pragma unroll
                for (int nt = 0; nt < 4; ++nt)
                    acc[mt][nt] = __builtin_amdgcn_mfma_f32_16x16x32_bf16(
                        af[mt], bf[nt], acc[mt][nt], 0, 0, 0);
        }
        __syncthreads();
    }

    float bv[4];
#pragma unroll
    for (int nt = 0; nt < 4; ++nt) bv[nt] = bias[col0 + wn + nt * 16 + m16];

    // ---- fused reduction epilogue: this wave owns chunk ch (64 cols) ----
    const int ch = (col0 + wn) >> 6;          // global chunk 0..9
#pragma unroll
    for (int mt = 0; mt < 4; ++mt) {
#pragma unroll
        for (int r = 0; r < 4; ++r) {
            float v0 = acc[mt][0][r] + bv[0];
            float v1 = acc[mt][1][r] + bv[1];
            float v2 = acc[mt][2][r] + bv[2];
            float v3 = acc[mt][3][r] + bv[3];
            float cmax = fmaxf(fmaxf(v0, v1), fmaxf(v2, v3));
#pragma unroll
            for (int off = 1; off <= 8; off <<= 1)
                cmax = fmaxf(cmax, __shfl_xor(cmax, off));   // over m16 lanes
            const float t = cmax - MARGIN;
            unsigned long long b0 = __ballot(v0 >= t);
            unsigned long long b1 = __ballot(v1 >= t);
            unsigned long long b2 = __ballot(v2 >= t);
            unsigned long long b3 = __ballot(v3 >= t);
            if (m16 == 0) {
                unsigned q16 = quad * 16;
                unsigned long long mask =
                      (((b0 >> q16) & 0xFFFFull))
                    | (((b1 >> q16) & 0xFFFFull) << 16)
                    | (((b2 >> q16) & 0xFFFFull) << 32)
                    | (((b3 >> q16) & 0xFFFFull) << 48);
                int token = tok0 + wm + mt * 16 + quad * 4 + r;
                uint4 e;
                e.x = __float_as_uint(cmax);
                e.y = (unsigned)(mask & 0xFFFFFFFFull);
                e.z = (unsigned)(mask >> 32);
                e.w = 0;
                meta[(size_t)token * 10 + ch] = e;
            }
        }
    }
}

// ---- decide: fast-path argmax from 5 chunk metas, else flag for rescore ----
__global__ __launch_bounds__(256) void k_decide(
    const uint4* __restrict__ meta, int* __restrict__ idx_out,
    int* __restrict__ hist, int* __restrict__ ctr, int* __restrict__ list)
{
    const int tg  = blockIdx.x * 256 + threadIdx.x;   // 65536
    const int tok = tg >> 1;
    const int grp = tg & 1;

    const uint4* mp = meta + (size_t)tok * 10 + grp * 5;
    float pm[5]; unsigned long long mk[5];
#pragma unroll
    for (int j = 0; j < 5; ++j) {
        uint4 e = mp[j];
        pm[j] = __uint_as_float(e.x);
        mk[j] = ((unsigned long long)e.z << 32) | e.y;
    }
    float M = fmaxf(fmaxf(fmaxf(pm[0], pm[1]), fmaxf(pm[2], pm[3])), pm[4]);
    const float thr = M - MARGIN;

    int nq = 0, qc = 0;
#pragma unroll
    for (int j = 0; j < 5; ++j)
        if (pm[j] >= thr) { ++nq; qc = j; }

    if (nq == 1 && __popcll(mk[qc]) == 1) {
        int col = qc * 64 + (__ffsll((long long)mk[qc]) - 1);
        idx_out[tg] = col;
        atomicAdd(&hist[grp * VDIM + col], 1);
    } else {
        int p = atomicAdd(ctr, 1);
        list[p] = tg;
    }
}

// ---- rescore: exact fp32 dot (coalesced via Wt32) for candidate cols ----
__global__ __launch_bounds__(256) void k_rescore(
    const uint4* __restrict__ meta, const float* __restrict__ hs,
    const float* __restrict__ Wt32, const float* __restrict__ bias,
    const int* __restrict__ list, const int* __restrict__ ctr,
    int* __restrict__ idx_out, int* __restrict__ hist)
{
    const int lane  = threadIdx.x & 63;
    const int wslot = blockIdx.x * 4 + (threadIdx.x >> 6);
    const int n = ctr[0];

    for (int it = wslot; it < n; it += 8192) {
        const int tg  = list[it];
        const int tok = tg >> 1;
        const int grp = tg & 1;

        const uint4* mp = meta + (size_t)tok * 10 + grp * 5;
        float pm[5]; unsigned long long mk[5];
#pragma unroll
        for (int j = 0; j < 5; ++j) {
            uint4 e = mp[j];
            pm[j] = __uint_as_float(e.x);
            mk[j] = ((unsigned long long)e.z << 32) | e.y;
        }
        float M = fmaxf(fmaxf(fmaxf(pm[0], pm[1]), fmaxf(pm[2], pm[3])), pm[4]);
        const float thr = M - MARGIN;

        float hsr[8];
#pragma unroll
        for (int i = 0; i < 8; ++i) hsr[i] = hs[(size_t)tok * 512 + i * 64 + lane];

        float bestv = -INFINITY;
        int   besti = 0;
#pragma unroll
        for (int j = 0; j < 5; ++j) {
            if (pm[j] < thr) continue;
            unsigned long long m = mk[j];
            while (m) {
                int b = __ffsll((long long)m) - 1; m &= m - 1;
                int col  = j * 64 + b;
                int gcol = grp * VDIM + col;
                const float* wrow = Wt32 + (size_t)gcol * 512;
                float p = 0.f;
#pragma unroll
                for (int i = 0; i < 8; ++i)
                    p = fmaf(hsr[i], wrow[i * 64 + lane], p);   // coalesced
#pragma unroll
                for (int off = 32; off >= 1; off >>= 1) p += __shfl_xor(p, off);
                float val = p + bias[gcol];
                if (val > bestv) { bestv = val; besti = col; }  // asc col => first-max
            }
        }
        if (lane == 0) {
            idx_out[tg] = besti;
            atomicAdd(&hist[grp * VDIM + besti], 1);
        }
    }
}

// ---------------- gather codevectors (all tokens) ----------------
__global__ __launch_bounds__(256) void k_gather(
    const float* __restrict__ cb, const int* __restrict__ idx,
    float* __restrict__ out)
{
    int tid  = threadIdx.x;
    int t    = blockIdx.x * 4 + (tid >> 6);
    int lane = tid & 63;
    int g    = lane >> 5;
    int q    = lane & 31;
    int i    = idx[t * 2 + g];
    const float4* src = (const float4*)(cb + (size_t)(g * VDIM + i) * DG);
    float4 v = src[q];
    ((float4*)(out + (size_t)t * 256))[g * 32 + q] = v;
}

// ---------------- perplexity ----------------
__global__ void k_perplex(const int* __restrict__ hist, float* __restrict__ out)
{
    __shared__ float sh[GVDIM];
    int t = threadIdx.x;
    float p = (float)hist[t] * (1.0f / (float)NTOK);
    sh[t] = p * logf(p + 1e-7f);
    __syncthreads();
    if (t == 0) {
        float s0 = 0.f, s1 = 0.f;
        for (int i = 0; i < VDIM; ++i)  s0 += sh[i];
        for (int i = VDIM; i < GVDIM; ++i) s1 += sh[i];
        out[0] = expf(-s0) + expf(-s1);
    }
}

extern "C" void kernel_launch(void* const* d_in, const int* in_sizes, int n_in,
                              void* d_out, int out_size, void* d_ws, size_t ws_size,
                              hipStream_t stream)
{
    const float* hs   = (const float*)d_in[0];
    const float* W    = (const float*)d_in[1];
    const float* bias = (const float*)d_in[2];
    const float* cb   = (const float*)d_in[3];

    unsigned short* hsb = (unsigned short*)d_ws;          // 32 MB
    unsigned short* wt  = hsb + 16777216;                 // 640 KB
    float* wt32         = (float*)(wt + 327680);          // 1.25 MB
    uint4* meta         = (uint4*)(wt32 + 327680);        // 5 MB
    int* idx            = (int*)(meta + 327680);          // 65,536 int
    int* hist           = idx + 65536;                    // 640 int
    int* ctr            = hist + GVDIM;                   // 1 int (+1 pad)
    int* list           = ctr + 2;                        // up to 65,536 int

    float* out  = (float*)d_out;
    float* perp = out + OUT0_SIZE;

    hipLaunchKernelGGL(k_cvt_hs,  dim3(8192),  dim3(256), 0, stream, hs, hsb);
    hipLaunchKernelGGL(k_cvt_wt,  dim3(GVDIM), dim3(256), 0, stream, W, wt, wt32, hist, ctr);
    hipLaunchKernelGGL(k_gemm,    dim3(1280),  dim3(256), 0, stream, hsb, wt, bias, meta);
    hipLaunchKernelGGL(k_decide,  dim3(256),   dim3(256), 0, stream,
                       meta, idx, hist, ctr, list);
    hipLaunchKernelGGL(k_rescore, dim3(2048),  dim3(256), 0, stream,
                       meta, hs, wt32, bias, list, ctr, idx, hist);
    hipLaunchKernelGGL(k_gather,  dim3(8192),  dim3(256), 0, stream, cb, idx, out);
    hipLaunchKernelGGL(k_perplex, dim3(1),     dim3(GVDIM), 0, stream, hist, perp);
}